// Round 8
// baseline (142.082 us; speedup 1.0000x reference)
//
#include <hip/hip_runtime.h>
#include <hip/hip_bf16.h>
#include <math.h>

// Problem constants (from reference): path_fea (131072, 64, 1, 1, 2) fp32
#define B_ROWS   131072
#define D_DIM    128          // 64 * 2
#define P_SAMP   16
#define G_GROUPS 8192         // B / P
#define T128     64           // 128-row tiles per dim (G / 128)
#define NTRI2    2080         // T128*(T128+1)/2 triangular block-tiles
#define K1_BLOCKS (G_GROUPS / 4)

typedef __bf16 bf16x8  __attribute__((ext_vector_type(8)));
typedef float  floatx4 __attribute__((ext_vector_type(4)));
typedef unsigned short u16x8 __attribute__((ext_vector_type(8)));

// Fragment-ordered center layout (written by K1, read by K2):
//   granule index = (row>>4)*256 + gg*16 + (row&15),  gg = k-octet 0..15
//   each granule = 8 bf16 (16 B). A 128-row panel = one CONTIGUOUS 32 KB
//   chunk -> coalesced staging / 1 KB contiguous wave fragment loads.

__device__ __forceinline__ float wave_red64(float v) {
    #pragma unroll
    for (int off = 32; off > 0; off >>= 1) v += __shfl_xor(v, off, 64);
    return v;
}

// sum over the 16-lane row via DPP row_ror rotations (VALU pipe, no DS):
// after ror:1,2,4,8 accumulate, every lane holds its row's 16-lane sum.
template <int CTRL>
__device__ __forceinline__ float dpp_ror_add(float v) {
    int r = __builtin_amdgcn_update_dpp(0, __builtin_bit_cast(int, v),
                                        CTRL, 0xf, 0xf, false);
    return v + __builtin_bit_cast(float, r);
}
__device__ __forceinline__ float row16_sum(float v) {
    v = dpp_ror_add<0x121>(v);   // row_ror:1
    v = dpp_ror_add<0x122>(v);   // row_ror:2
    v = dpp_ror_add<0x124>(v);   // row_ror:4
    v = dpp_ror_add<0x128>(v);   // row_ror:8
    return v;
}

// ---------------------------------------------------------------------------
// K1: per-group centers (bf16, fragment layout) + |center|^2 + intra hinge.
// One wave per group; all global loads are 1KB-contiguous wave-loads.
// Reduction: 4 DPP stages (within 16 lanes) + 1 shuffle (x16) instead of
// 5 DS-swizzle stages -> DS ops/wave ~51 -> ~15.
// ---------------------------------------------------------------------------
__global__ __launch_bounds__(256) void k_center_intra(
    const float* __restrict__ x,            // [B, 128]
    uint2* __restrict__ cfrag,               // [G*32] 8B halves of granules
    float* __restrict__ sq,                  // [G]
    float* __restrict__ partial,             // [K1_BLOCKS] intra partials
    float* __restrict__ acc,                 // acc[0] zeroed here
    unsigned int* __restrict__ done)         // K2 ticket, zeroed here
{
    const int wave = threadIdx.x >> 6;
    const int lane = threadIdx.x & 63;
    const int half = lane >> 5;      // sample parity this lane owns
    const int c    = lane & 31;      // dim-quad index (4 dims per lane)
    const int g    = blockIdx.x * 4 + wave;

    if (blockIdx.x == 0 && threadIdx.x == 0) { acc[0] = 0.f; *done = 0u; }

    // sample s = 2*l + half, dims 4c..4c+3
    const float* base = x + (size_t)g * (P_SAMP * D_DIM) + half * D_DIM + c * 4;

    floatx4 v[8];
    #pragma unroll
    for (int l = 0; l < 8; ++l)
        v[l] = *(const floatx4*)(base + l * (2 * D_DIM));

    floatx4 cs = v[0];
    #pragma unroll
    for (int l = 1; l < 8; ++l) cs += v[l];
    #pragma unroll
    for (int k = 0; k < 4; ++k) cs[k] += __shfl_xor(cs[k], 32, 64);
    floatx4 ctr = cs * (1.0f / P_SAMP);

    // 9 parallel partial sums: 8 sample dists + center sq-norm
    float p[9];
    #pragma unroll
    for (int l = 0; l < 8; ++l) {
        floatx4 d = v[l] - ctr;
        p[l] = d[0]*d[0] + d[1]*d[1] + d[2]*d[2] + d[3]*d[3];
    }
    p[8] = ctr[0]*ctr[0] + ctr[1]*ctr[1] + ctr[2]*ctr[2] + ctr[3]*ctr[3];

    // reduce over 32-lane half: 16-lane DPP sum, then combine the two rows
    #pragma unroll
    for (int s = 0; s < 9; ++s) {
        p[s] = row16_sum(p[s]);
        p[s] += __shfl_xor(p[s], 16, 64);
    }
    // p[l] = full 128-dim dist^2 of sample 2l+half; p[8] = |center|^2

    // store bf16 center into fragment layout (8 B per lane, half 0 only)
    if (half == 0) {
        unsigned int b0 = __builtin_bit_cast(unsigned short, (__bf16)ctr[0]);
        unsigned int b1 = __builtin_bit_cast(unsigned short, (__bf16)ctr[1]);
        unsigned int b2 = __builtin_bit_cast(unsigned short, (__bf16)ctr[2]);
        unsigned int b3 = __builtin_bit_cast(unsigned short, (__bf16)ctr[3]);
        uint2 pk;
        pk.x = (b1 << 16) | b0;
        pk.y = (b3 << 16) | b2;
        const int gran = (g >> 4) * 256 + (c >> 1) * 16 + (g & 15);
        cfrag[gran * 2 + (c & 1)] = pk;
    }
    if (lane == 0) sq[g] = p[8];

    float isum = 0.f;
    #pragma unroll
    for (int l = 0; l < 8; ++l) {
        float d = sqrtf(p[l]);
        float t = fmaxf(d - 0.1f, 0.f);
        isum += t * t;
    }
    isum += __shfl_xor(isum, 32, 64);

    __shared__ float sh[4];
    if (lane == 0) sh[wave] = isum;
    __syncthreads();
    if (threadIdx.x == 0)
        partial[blockIdx.x] = sh[0] + sh[1] + sh[2] + sh[3];
}

// ---------------------------------------------------------------------------
// K2: inter hinge (R7 structure) + fused finalize. One BLOCK per 128x128
// triangular tile; A panel staged to LDS once, B fragments streamed
// direct-to-register (k-batch double-buffered, issued before the barrier).
// The LAST block to finish (device-scope ticket) reduces K1's intra
// partials and writes both outputs — K3 dispatch eliminated.
// ---------------------------------------------------------------------------
__global__ __launch_bounds__(256, 3) void k_inter(
    const u16x8* __restrict__ cfrag,         // granule array (16 B each)
    const float* __restrict__ sq,            // [G]
    float* __restrict__ acc,                 // acc[0] = inter hinge sum
    const float* __restrict__ partial,       // [K1_BLOCKS] intra partials
    float* __restrict__ out,                 // out[0]=inter, out[1]=intra
    unsigned int* __restrict__ done)         // arrival ticket
{
    __shared__ u16x8 smemA[2048];   // 32 KB: A panel, fragment order
    __shared__ float shred[4];
    __shared__ int   shlast;

    // triangular decode over T128=64: off(i) = 64i - i(i-1)/2
    const int bid = blockIdx.x;
    float sf = sqrtf(64.5f * 64.5f - 2.0f * (float)bid);
    int ti = (int)(64.5f - sf);
    if (ti < 0) ti = 0;
    if (ti > T128 - 1) ti = T128 - 1;
    #define TRI_OFF(i) ((i) * T128 - (((i) * ((i) - 1)) >> 1))
    while (ti > 0 && TRI_OFF(ti) > bid) --ti;
    while (ti < T128 - 1 && TRI_OFF(ti + 1) <= bid) ++ti;
    const int tj = ti + (bid - TRI_OFF(ti));
    #undef TRI_OFF

    const int t    = threadIdx.x;
    const int wave = t >> 6;
    const int lane = t & 63;
    const int wr   = wave >> 1;    // 0..1: which 64-row half of i
    const int wc   = wave & 1;     // 0..1: which 64-col half of j
    const int lrow = lane & 15;
    const int quad = lane >> 4;

    const int i0 = ti * 128 + wr * 64;
    const int j0 = tj * 128 + wc * 64;

    // ---- issue B batches 0/1 + sq loads FIRST (independent of LDS) ----
    #define BIDX(nt, ks) (((size_t)tj * 8 + wc * 4 + (nt)) * 256 + ((ks) * 4 + quad) * 16 + lrow)
    bf16x8 bb[2][4];
    #pragma unroll
    for (int pb = 0; pb < 2; ++pb)
        #pragma unroll
        for (int nt = 0; nt < 4; ++nt)
            bb[pb][nt] = __builtin_bit_cast(bf16x8, cfrag[BIDX(nt, pb)]);

    floatx4 sqi[4];
    float   sqj[4];
    #pragma unroll
    for (int mt = 0; mt < 4; ++mt)
        sqi[mt] = *(const floatx4*)(sq + i0 + mt * 16 + quad * 4);
    #pragma unroll
    for (int nt = 0; nt < 4; ++nt)
        sqj[nt] = sq[j0 + nt * 16 + lrow];

    // ---- stage A panel (rows ti*128..+128): one contiguous 32 KB chunk ----
    const size_t abase = (size_t)ti * 2048;
    #pragma unroll
    for (int it = 0; it < 8; ++it)
        smemA[t + it * 256] = cfrag[abase + t + it * 256];
    __syncthreads();

    const bool bdiag = (ti == tj);
    const bool skipq = (bdiag && wr > wc);   // strictly-lower quadrant (i>j)

    float hsum = 0.f;
    if (!skipq) {
        floatx4 c4[4][4] = {};   // 16 accumulator tiles of 16x16

        #pragma unroll
        for (int ks = 0; ks < 4; ++ks) {     // K = 128, 32 per MFMA
            const int cur = ks & 1;
            bf16x8 a[4];
            const int go = (ks * 4 + quad) * 16 + lrow;
            #pragma unroll
            for (int mt = 0; mt < 4; ++mt)
                a[mt] = __builtin_bit_cast(bf16x8, smemA[(wr * 4 + mt) * 256 + go]);
            #pragma unroll
            for (int mt = 0; mt < 4; ++mt)
                #pragma unroll
                for (int nt = 0; nt < 4; ++nt)
                    c4[mt][nt] = __builtin_amdgcn_mfma_f32_16x16x32_bf16(
                                    a[mt], bb[cur][nt], c4[mt][nt], 0, 0, 0);
            if (ks < 2) {                    // refill with batch ks+2
                #pragma unroll
                for (int nt = 0; nt < 4; ++nt)
                    bb[cur][nt] = __builtin_bit_cast(bf16x8, cfrag[BIDX(nt, ks + 2)]);
            }
        }

        // Epilogue: d2 = sq[i]+sq[j]-2*gram; hinge nonzero only when d2 < 1.
        const bool qdiag = (bdiag && wr == wc);
        #pragma unroll
        for (int mt = 0; mt < 4; ++mt) {
            #pragma unroll
            for (int nt = 0; nt < 4; ++nt) {
                const int ib = i0 + mt * 16 + quad * 4;
                const int j  = j0 + nt * 16 + lrow;
                #pragma unroll
                for (int r = 0; r < 4; ++r) {
                    if (qdiag && j <= ib + r) continue;
                    float d2 = sqi[mt][r] + sqj[nt] - 2.0f * c4[mt][nt][r];
                    if (d2 < 1.0f) {         // rare path
                        float d = sqrtf(fmaxf(d2, 0.f));
                        float tt = 1.0f - d;
                        hsum += tt * tt;
                    }
                }
            }
        }
    }
    #undef BIDX

    if (__ballot(hsum != 0.f)) {
        hsum = wave_red64(hsum);
        if (lane == 0) atomicAdd(acc, hsum);
    }

    // ---- completion ticket: last block finalizes both outputs ----
    __syncthreads();                          // all 4 waves' atomics issued
    if (t == 0) {
        __threadfence();                      // release our contribution
        unsigned int old = atomicAdd(done, 1u);
        shlast = (old == (unsigned int)(NTRI2 - 1)) ? 1 : 0;
    }
    __syncthreads();
    if (shlast) {
        __threadfence();                      // acquire all contributions
        float s = 0.f;
        for (int i = t; i < K1_BLOCKS; i += 256) s += partial[i];
        s = wave_red64(s);
        if (lane == 0) shred[wave] = s;
        __syncthreads();
        if (t == 0) {
            const float n_pairs = (float)G_GROUPS * (float)(G_GROUPS - 1) * 0.5f;
            out[0] = acc[0] / n_pairs;                                     // inter
            out[1] = (shred[0] + shred[1] + shred[2] + shred[3]) / (float)B_ROWS;
        }
    }
}

extern "C" void kernel_launch(void* const* d_in, const int* in_sizes, int n_in,
                              void* d_out, int out_size, void* d_ws, size_t ws_size,
                              hipStream_t stream) {
    const float* x = (const float*)d_in[0];
    float* out = (float*)d_out;

    // workspace layout
    float*        acc     = (float*)d_ws;                          // 4 B
    unsigned int* done    = (unsigned int*)((char*)d_ws + 128);    // 4 B
    float*        partial = (float*)((char*)d_ws + 256);           // 8 KB
    float*        sq      = (float*)((char*)d_ws + 16384);         // 32 KB
    uint2*        cfrag   = (uint2*)((char*)d_ws + 65536);         // 2 MB

    k_center_intra<<<K1_BLOCKS, 256, 0, stream>>>(x, cfrag, sq, partial, acc, done);

    k_inter<<<NTRI2, 256, 0, stream>>>((const u16x8*)cfrag, sq, acc,
                                       partial, out, done);
}

// Round 9
// 111.158 us; speedup vs baseline: 1.2782x; 1.2782x over previous
//
#include <hip/hip_runtime.h>
#include <hip/hip_bf16.h>
#include <math.h>

// Problem constants (from reference): path_fea (131072, 64, 1, 1, 2) fp32
#define B_ROWS   131072
#define D_DIM    128          // 64 * 2
#define P_SAMP   16
#define G_GROUPS 8192         // B / P
#define T128     64           // 128-row tiles per dim (G / 128)
#define NTRI2    2080         // T128*(T128+1)/2 triangular block-tiles
#define K1_BLOCKS (G_GROUPS / 4)

typedef __bf16 bf16x8  __attribute__((ext_vector_type(8)));
typedef float  floatx4 __attribute__((ext_vector_type(4)));
typedef unsigned short u16x8 __attribute__((ext_vector_type(8)));

// Fragment-ordered center layout (written by K1, read by K2):
//   granule index = (row>>4)*256 + gg*16 + (row&15),  gg = k-octet 0..15
//   each granule = 8 bf16 (16 B). A 128-row panel = one CONTIGUOUS 32 KB
//   chunk -> coalesced staging / 1 KB contiguous wave fragment loads.

__device__ __forceinline__ float wave_red64(float v) {
    #pragma unroll
    for (int off = 32; off > 0; off >>= 1) v += __shfl_xor(v, off, 64);
    return v;
}

// sum over the 16-lane row via DPP row_ror rotations (VALU pipe, no DS)
template <int CTRL>
__device__ __forceinline__ float dpp_ror_add(float v) {
    int r = __builtin_amdgcn_update_dpp(0, __builtin_bit_cast(int, v),
                                        CTRL, 0xf, 0xf, false);
    return v + __builtin_bit_cast(float, r);
}
__device__ __forceinline__ float row16_sum(float v) {
    v = dpp_ror_add<0x121>(v);   // row_ror:1
    v = dpp_ror_add<0x122>(v);   // row_ror:2
    v = dpp_ror_add<0x124>(v);   // row_ror:4
    v = dpp_ror_add<0x128>(v);   // row_ror:8
    return v;
}

// ---------------------------------------------------------------------------
// K1: per-group centers (bf16, fragment layout) + |center|^2 + intra hinge.
// One wave per group; all global loads are 1KB-contiguous wave-loads.
// Reduction: 4 DPP stages + 1 shuffle (x16) + 1 shuffle (x32).
// ---------------------------------------------------------------------------
__global__ __launch_bounds__(256) void k_center_intra(
    const float* __restrict__ x,            // [B, 128]
    uint2* __restrict__ cfrag,               // [G*32] 8B halves of granules
    float* __restrict__ sq,                  // [G]
    float* __restrict__ partial,             // [K1_BLOCKS] intra partials
    float* __restrict__ acc)                 // acc[0] zeroed here
{
    const int wave = threadIdx.x >> 6;
    const int lane = threadIdx.x & 63;
    const int half = lane >> 5;      // sample parity this lane owns
    const int c    = lane & 31;      // dim-quad index (4 dims per lane)
    const int g    = blockIdx.x * 4 + wave;

    if (blockIdx.x == 0 && threadIdx.x == 0) acc[0] = 0.f;   // K2's accumulator

    // sample s = 2*l + half, dims 4c..4c+3
    const float* base = x + (size_t)g * (P_SAMP * D_DIM) + half * D_DIM + c * 4;

    floatx4 v[8];
    #pragma unroll
    for (int l = 0; l < 8; ++l)
        v[l] = *(const floatx4*)(base + l * (2 * D_DIM));

    floatx4 cs = v[0];
    #pragma unroll
    for (int l = 1; l < 8; ++l) cs += v[l];
    #pragma unroll
    for (int k = 0; k < 4; ++k) cs[k] += __shfl_xor(cs[k], 32, 64);
    floatx4 ctr = cs * (1.0f / P_SAMP);

    // 9 parallel partial sums: 8 sample dists + center sq-norm
    float p[9];
    #pragma unroll
    for (int l = 0; l < 8; ++l) {
        floatx4 d = v[l] - ctr;
        p[l] = d[0]*d[0] + d[1]*d[1] + d[2]*d[2] + d[3]*d[3];
    }
    p[8] = ctr[0]*ctr[0] + ctr[1]*ctr[1] + ctr[2]*ctr[2] + ctr[3]*ctr[3];

    #pragma unroll
    for (int s = 0; s < 9; ++s) {
        p[s] = row16_sum(p[s]);
        p[s] += __shfl_xor(p[s], 16, 64);
    }
    // p[l] = full 128-dim dist^2 of sample 2l+half; p[8] = |center|^2

    // store bf16 center into fragment layout (8 B per lane, half 0 only)
    if (half == 0) {
        unsigned int b0 = __builtin_bit_cast(unsigned short, (__bf16)ctr[0]);
        unsigned int b1 = __builtin_bit_cast(unsigned short, (__bf16)ctr[1]);
        unsigned int b2 = __builtin_bit_cast(unsigned short, (__bf16)ctr[2]);
        unsigned int b3 = __builtin_bit_cast(unsigned short, (__bf16)ctr[3]);
        uint2 pk;
        pk.x = (b1 << 16) | b0;
        pk.y = (b3 << 16) | b2;
        const int gran = (g >> 4) * 256 + (c >> 1) * 16 + (g & 15);
        cfrag[gran * 2 + (c & 1)] = pk;
    }
    if (lane == 0) sq[g] = p[8];

    float isum = 0.f;
    #pragma unroll
    for (int l = 0; l < 8; ++l) {
        float d = sqrtf(p[l]);
        float t = fmaxf(d - 0.1f, 0.f);
        isum += t * t;
    }
    isum += __shfl_xor(isum, 32, 64);

    __shared__ float sh[4];
    if (lane == 0) sh[wave] = isum;
    __syncthreads();
    if (threadIdx.x == 0)
        partial[blockIdx.x] = sh[0] + sh[1] + sh[2] + sh[3];
}

// ---------------------------------------------------------------------------
// K2: inter hinge. One BLOCK per 128x128 triangular tile (2080 blocks);
// 4 waves = 64x64 quadrants. ALL FOUR B k-batches (16 contiguous 1 KB
// wave-loads) + sq values issued upfront, then A panel staged to LDS
// (one contiguous 32 KB chunk) — exactly ONE load-latency generation per
// wave, everything in flight before the single barrier. No ticket/fence
// (R8 showed that costs ~30 us).
// ---------------------------------------------------------------------------
__global__ __launch_bounds__(256, 3) void k_inter(
    const u16x8* __restrict__ cfrag,         // granule array (16 B each)
    const float* __restrict__ sq,            // [G]
    float* __restrict__ acc)                 // acc[0] = inter hinge sum
{
    __shared__ u16x8 smemA[2048];   // 32 KB: A panel, fragment order

    // triangular decode over T128=64: off(i) = 64i - i(i-1)/2
    const int bid = blockIdx.x;
    float sf = sqrtf(64.5f * 64.5f - 2.0f * (float)bid);
    int ti = (int)(64.5f - sf);
    if (ti < 0) ti = 0;
    if (ti > T128 - 1) ti = T128 - 1;
    #define TRI_OFF(i) ((i) * T128 - (((i) * ((i) - 1)) >> 1))
    while (ti > 0 && TRI_OFF(ti) > bid) --ti;
    while (ti < T128 - 1 && TRI_OFF(ti + 1) <= bid) ++ti;
    const int tj = ti + (bid - TRI_OFF(ti));
    #undef TRI_OFF

    const int t    = threadIdx.x;
    const int wave = t >> 6;
    const int lane = t & 63;
    const int wr   = wave >> 1;    // 0..1: which 64-row half of i
    const int wc   = wave & 1;     // 0..1: which 64-col half of j
    const int lrow = lane & 15;
    const int quad = lane >> 4;

    const int i0 = ti * 128 + wr * 64;
    const int j0 = tj * 128 + wc * 64;

    // ---- issue ALL B batches + sq loads FIRST (independent of LDS) ----
    #define BIDX(nt, ks) (((size_t)tj * 8 + wc * 4 + (nt)) * 256 + ((ks) * 4 + quad) * 16 + lrow)
    bf16x8 bb[4][4];
    #pragma unroll
    for (int ks = 0; ks < 4; ++ks)
        #pragma unroll
        for (int nt = 0; nt < 4; ++nt)
            bb[ks][nt] = __builtin_bit_cast(bf16x8, cfrag[BIDX(nt, ks)]);
    #undef BIDX

    floatx4 sqi[4];
    float   sqj[4];
    #pragma unroll
    for (int mt = 0; mt < 4; ++mt)
        sqi[mt] = *(const floatx4*)(sq + i0 + mt * 16 + quad * 4);
    #pragma unroll
    for (int nt = 0; nt < 4; ++nt)
        sqj[nt] = sq[j0 + nt * 16 + lrow];

    // ---- stage A panel (rows ti*128..+128): one contiguous 32 KB chunk ----
    const size_t abase = (size_t)ti * 2048;
    #pragma unroll
    for (int it = 0; it < 8; ++it)
        smemA[t + it * 256] = cfrag[abase + t + it * 256];
    __syncthreads();

    const bool bdiag = (ti == tj);
    if (bdiag && wr > wc) return;            // strictly-lower quadrant (i>j)

    floatx4 c4[4][4] = {};   // 16 accumulator tiles of 16x16

    #pragma unroll
    for (int ks = 0; ks < 4; ++ks) {         // K = 128, 32 per MFMA
        bf16x8 a[4];
        const int go = (ks * 4 + quad) * 16 + lrow;
        #pragma unroll
        for (int mt = 0; mt < 4; ++mt)
            a[mt] = __builtin_bit_cast(bf16x8, smemA[(wr * 4 + mt) * 256 + go]);
        #pragma unroll
        for (int mt = 0; mt < 4; ++mt)
            #pragma unroll
            for (int nt = 0; nt < 4; ++nt)
                c4[mt][nt] = __builtin_amdgcn_mfma_f32_16x16x32_bf16(
                                a[mt], bb[ks][nt], c4[mt][nt], 0, 0, 0);
    }

    // Epilogue: d2 = sq[i]+sq[j]-2*gram; hinge nonzero only when d2 < 1.
    const bool qdiag = (bdiag && wr == wc);
    float hsum = 0.f;
    #pragma unroll
    for (int mt = 0; mt < 4; ++mt) {
        #pragma unroll
        for (int nt = 0; nt < 4; ++nt) {
            const int ib = i0 + mt * 16 + quad * 4;
            const int j  = j0 + nt * 16 + lrow;
            #pragma unroll
            for (int r = 0; r < 4; ++r) {
                if (qdiag && j <= ib + r) continue;
                float d2 = sqi[mt][r] + sqj[nt] - 2.0f * c4[mt][nt][r];
                if (d2 < 1.0f) {             // rare path
                    float d = sqrtf(fmaxf(d2, 0.f));
                    float tt = 1.0f - d;
                    hsum += tt * tt;
                }
            }
        }
    }
    if (__ballot(hsum != 0.f)) {
        hsum = wave_red64(hsum);
        if (lane == 0) atomicAdd(acc, hsum);
    }
}

// ---------------------------------------------------------------------------
// K3: reduce K1 partials, finalize both outputs.
// ---------------------------------------------------------------------------
__global__ __launch_bounds__(256) void k_final(
    const float* __restrict__ acc,
    const float* __restrict__ partial,
    float* __restrict__ out)
{
    __shared__ float sh[4];
    float s = 0.f;
    for (int i = threadIdx.x; i < K1_BLOCKS; i += 256) s += partial[i];
    s = wave_red64(s);
    const int wave = threadIdx.x >> 6;
    const int lane = threadIdx.x & 63;
    if (lane == 0) sh[wave] = s;
    __syncthreads();
    if (threadIdx.x == 0) {
        const float n_pairs = (float)G_GROUPS * (float)(G_GROUPS - 1) * 0.5f;
        out[0] = acc[0] / n_pairs;                                 // inter
        out[1] = (sh[0] + sh[1] + sh[2] + sh[3]) / (float)B_ROWS;  // intra
    }
}

extern "C" void kernel_launch(void* const* d_in, const int* in_sizes, int n_in,
                              void* d_out, int out_size, void* d_ws, size_t ws_size,
                              hipStream_t stream) {
    const float* x = (const float*)d_in[0];
    float* out = (float*)d_out;

    // workspace layout
    float* acc     = (float*)d_ws;                          // 4 B
    float* partial = (float*)((char*)d_ws + 256);           // 8 KB
    float* sq      = (float*)((char*)d_ws + 16384);         // 32 KB
    uint2* cfrag   = (uint2*)((char*)d_ws + 65536);         // 2 MB bf16 centers

    k_center_intra<<<K1_BLOCKS, 256, 0, stream>>>(x, cfrag, sq, partial, acc);

    k_inter<<<NTRI2, 256, 0, stream>>>((const u16x8*)cfrag, sq, acc);

    k_final<<<1, 256, 0, stream>>>(acc, partial, out);
}